// Round 13
// baseline (568.806 us; speedup 1.0000x reference)
//
#include <hip/hip_runtime.h>
#include <stdint.h>

#define QN    300
#define WN    10
#define CD    640
#define IJ    196
#define MROWS 1960              // WN*IJ
#define NTOT  58800             // QN*IJ
#define OUTQ  384160            // MROWS*IJ
#define EPSV  1e-8f

#define BM    256
#define BN    256
#define BK    64
#define BUFE  ((BM + BN) * BK)         // 32768 ushorts = 64 KB per buffer
#define NTK   (CD / BK)                // 10 K-tiles

#define MT_TILES 8                     // m tiles of 256 (pad 2048)
#define NT_TILES 230                   // n tiles of 256 (pad 58880)
#define NWG      (MT_TILES * NT_TILES) // 1840, divisible by 8
#define CPX      (NWG / 8)             // 230

typedef __attribute__((ext_vector_type(8))) short bf16x8;
typedef __attribute__((ext_vector_type(4))) float f32x4;

__device__ __forceinline__ unsigned short f2bf(float f) {
    uint32_t u = __float_as_uint(f);
    u += 0x7FFFu + ((u >> 16) & 1u);   // RNE
    return (unsigned short)(u >> 16);
}

__device__ __forceinline__ void gload16(const void* g, void* l) {
    __builtin_amdgcn_global_load_lds(
        (const __attribute__((address_space(1))) void*)g,
        (__attribute__((address_space(3))) void*)l,
        16, 0, 0);
}

// ---------------------------------------------------------------------------
// Combined pre-pass (ONE launch, round-10 verified): X[b][640][196] fp32 ->
// XT[row][640] bf16 (k contiguous) with the 3-bit swizzle baked per 16B unit
// within each 8-unit (64-elem) K-group: stored_unit = (u&8)|((u&7)^(row&7)),
// plus fp32 norms.  grid = (4, 310): y<300 -> query, else proto.
// ---------------------------------------------------------------------------
__global__ __launch_bounds__(256)
void prep_all(const float* __restrict__ proto, const float* __restrict__ query,
              uint4* __restrict__ pT, uint4* __restrict__ qT,
              float* __restrict__ pn, float* __restrict__ qn)
{
    __shared__ float T[128][65];
    __shared__ float ssL[64][17];

    const int bi = blockIdx.y;
    const bool isQ = (bi < QN);
    const int b  = isQ ? bi : bi - QN;
    const float* Xb = (isQ ? query : proto) + (size_t)b * (CD * IJ);
    uint4* XT   = isQ ? qT : pT;
    float* nrm  = isQ ? qn : pn;
    const int rowbase = b * IJ;

    const int i0 = blockIdx.x * 64;
    const int t  = threadIdx.x;

    const int cg = t >> 4;
    const int i4 = (t & 15) * 4;
    const int iv = i0 + i4;
    const bool liv = (iv <= IJ - 4);

    const int u   = t & 15;
    const int ilb = (t >> 4) * 4;

    float ss[4] = {0.f, 0.f, 0.f, 0.f};

    for (int cc = 0; cc < CD / 128; ++cc) {
        #pragma unroll
        for (int pass = 0; pass < 8; ++pass) {
            int cl = pass * 16 + cg;
            int c  = cc * 128 + cl;
            float4 v = make_float4(0.f, 0.f, 0.f, 0.f);
            if (liv) v = *(const float4*)&Xb[(size_t)c * IJ + iv];
            T[cl][i4 + 0] = v.x; T[cl][i4 + 1] = v.y;
            T[cl][i4 + 2] = v.z; T[cl][i4 + 3] = v.w;
        }
        __syncthreads();
        #pragma unroll
        for (int j = 0; j < 4; ++j) {
            int il = ilb + j;
            float v[8];
            #pragma unroll
            for (int r = 0; r < 8; ++r) { v[r] = T[u * 8 + r][il]; ss[j] += v[r] * v[r]; }
            int ig = i0 + il;
            if (ig < IJ) {
                union { unsigned short s[8]; uint4 q; } pk;
                #pragma unroll
                for (int r = 0; r < 8; ++r) pk.s[r] = f2bf(v[r]);
                int rowg = rowbase + ig;
                int us = (u & 8) | ((u & 7) ^ (rowg & 7));
                XT[(size_t)rowg * (CD / 8) + cc * 16 + us] = pk.q;
            }
        }
        __syncthreads();
    }

    #pragma unroll
    for (int j = 0; j < 4; ++j) ssL[ilb + j][u] = ss[j];
    __syncthreads();
    if (t < 64) {
        int ig = i0 + t;
        if (ig < IJ) {
            float s = 0.f;
            #pragma unroll
            for (int k = 0; k < 16; ++k) s += ssL[t][k];
            nrm[rowbase + ig] = sqrtf(s);
        }
    }
}

// ---------------------------------------------------------------------------
// GEMM (round-10 best structure + 2 micro-opts).  C[m][n] = sum AT[m]*BT[n].
// 256x256 tile, BK=64, 8 waves (2M x 4N), per-wave 128x64 (acc[8][4]).
// 6 phases per 2 K-tiles (P2+P3 / P6+P7 merged via a second A reg-set ag[8]:
// both quadrant reads issue under ONE barrier+lgkm0, both b1-MFMA quadrants
// run back-to-back -> 2 fewer barriers per iteration).  Counted vmcnt gates
// (VMC(2), never 0 in loop): 8 loads issued per half-iter, gate leaves the
// newest pair in flight -- identical accounting to round 8/10.
// Nontemporal f32x4 epilogue stores (zero-reuse output stream; keeps B
// panels L2-resident).
// ---------------------------------------------------------------------------
__global__ __launch_bounds__(512, 2)
void gemm_kernel(const uint4* __restrict__ AT, const uint4* __restrict__ BT,
                 const float* __restrict__ pn, const float* __restrict__ qn,
                 float* __restrict__ out)
{
    __shared__ unsigned short lds[2 * BUFE];   // 128 KB

    const int bid = blockIdx.x;
    const int swz = (bid & 7) * CPX + (bid >> 3);   // bijective (1840%8==0)
    const int mt  = swz & (MT_TILES - 1);
    const int nt  = swz >> 3;
    const int m0  = mt * BM;
    const int n0  = nt * BN;

    const int t  = threadIdx.x;
    const int w  = t >> 6, l = t & 63;
    const int fr = l & 15, fq = l >> 4;
    const int wm0 = (w >> 2) * 128;   // 2 M-waves
    const int wn0 = (w & 3) * 64;     // 4 N-waves

    const int lr = l >> 3, lu = l & 7;
    int ra00 = m0 +   0 + w * 8 + lr; if (ra00 > MROWS - 1) ra00 = MROWS - 1;
    int ra01 = m0 +  64 + w * 8 + lr; if (ra01 > MROWS - 1) ra01 = MROWS - 1;
    int ra10 = m0 + 128 + w * 8 + lr; if (ra10 > MROWS - 1) ra10 = MROWS - 1;
    int ra11 = m0 + 192 + w * 8 + lr; if (ra11 > MROWS - 1) ra11 = MROWS - 1;
    int rb00 = n0 +   0 + w * 8 + lr; if (rb00 > NTOT - 1) rb00 = NTOT - 1;
    int rb01 = n0 +  64 + w * 8 + lr; if (rb01 > NTOT - 1) rb01 = NTOT - 1;
    int rb10 = n0 + 128 + w * 8 + lr; if (rb10 > NTOT - 1) rb10 = NTOT - 1;
    int rb11 = n0 + 192 + w * 8 + lr; if (rb11 > NTOT - 1) rb11 = NTOT - 1;
    const uint4* ga00 = AT + (size_t)ra00 * 80 + lu;
    const uint4* ga01 = AT + (size_t)ra01 * 80 + lu;
    const uint4* ga10 = AT + (size_t)ra10 * 80 + lu;
    const uint4* ga11 = AT + (size_t)ra11 * 80 + lu;
    const uint4* gb00 = BT + (size_t)rb00 * 80 + lu;
    const uint4* gb01 = BT + (size_t)rb01 * 80 + lu;
    const uint4* gb10 = BT + (size_t)rb10 * 80 + lu;
    const uint4* gb11 = BT + (size_t)rb11 * 80 + lu;
    const int la00 = (  0 + w * 8) * 64;
    const int la01 = ( 64 + w * 8) * 64;
    const int la10 = (128 + w * 8) * 64;
    const int la11 = (192 + w * 8) * 64;
    const int lb00 = BM * 64 + (  0 + w * 8) * 64;
    const int lb01 = BM * 64 + ( 64 + w * 8) * 64;
    const int lb10 = BM * 64 + (128 + w * 8) * 64;
    const int lb11 = BM * 64 + (192 + w * 8) * 64;

    const int fqS0 = fq << 3;
    const int fqS1 = (fq + 4) << 3;
    int baA[8], kyA[8], baB[4], kyB[4];
    #pragma unroll
    for (int i = 0; i < 8; ++i) {
        int rowa = wm0 + i * 16 + fr;
        baA[i] = rowa * 64;  kyA[i] = (rowa & 7) << 3;
    }
    #pragma unroll
    for (int i = 0; i < 4; ++i) {
        int rowb = wn0 + i * 16 + fr;
        baB[i] = BM * 64 + rowb * 64;  kyB[i] = (rowb & 7) << 3;
    }

    f32x4 acc[8][4];
    #pragma unroll
    for (int a = 0; a < 8; ++a)
        #pragma unroll
        for (int bb = 0; bb < 4; ++bb)
            acc[a][bb] = (f32x4){0.f, 0.f, 0.f, 0.f};

#define ST2(PA, PB, LA, LB)                                               \
    gload16(PA, (char*)&lds[(LA)]); PA += 8;                              \
    gload16(PB, (char*)&lds[(LB)]); PB += 8;

#define RD_A(AF, OC, G)                                                   \
    _Pragma("unroll")                                                     \
    for (int mm = 0; mm < 4; ++mm) {                                      \
        AF[mm]   = *(const bf16x8*)&lds[(OC) + baA[(G)+mm]                \
                                        + (fqS0 ^ kyA[(G)+mm])];          \
        AF[4+mm] = *(const bf16x8*)&lds[(OC) + baA[(G)+mm]                \
                                        + (fqS1 ^ kyA[(G)+mm])];          \
    }
#define RD_B(BV, OC, G)                                                   \
    _Pragma("unroll")                                                     \
    for (int nn = 0; nn < 2; ++nn) {                                      \
        BV[nn]   = *(const bf16x8*)&lds[(OC) + baB[(G)+nn]                \
                                        + (fqS0 ^ kyB[(G)+nn])];          \
        BV[2+nn] = *(const bf16x8*)&lds[(OC) + baB[(G)+nn]                \
                                        + (fqS1 ^ kyB[(G)+nn])];          \
    }
#define MF(MB, NB, BV, AF)                                                \
    _Pragma("unroll")                                                     \
    for (int ks = 0; ks < 2; ++ks)                                        \
        _Pragma("unroll")                                                 \
        for (int mm = 0; mm < 4; ++mm)                                    \
            _Pragma("unroll")                                             \
            for (int nn = 0; nn < 2; ++nn)                                \
                acc[(MB)+mm][(NB)+nn] =                                   \
                    __builtin_amdgcn_mfma_f32_16x16x32_bf16(              \
                        BV[ks*2+nn], AF[ks*4+mm],                         \
                        acc[(MB)+mm][(NB)+nn], 0, 0, 0);

#define BAR    __builtin_amdgcn_s_barrier()
#define LGKM0  do { asm volatile("s_waitcnt lgkmcnt(0)" ::: "memory");    \
                    __builtin_amdgcn_sched_barrier(0); } while (0)
#define VMC(N) asm volatile("s_waitcnt vmcnt(" #N ")" ::: "memory")
#define PRIO1  __builtin_amdgcn_s_setprio(1)
#define PRIO0  __builtin_amdgcn_s_setprio(0)

    // prologue: tile0 fully -> buf0; tile1's A0 -> buf1.  10 loads;
    // VMC(2): tile0's 8 landed, tile1-A0 pair in flight.
    ST2(ga00, ga01, la00, la01);               // t0 A0
    ST2(gb00, gb01, lb00, lb01);               // t0 B0
    ST2(ga10, ga11, la10, la11);               // t0 A1
    ST2(gb10, gb11, lb10, lb11);               // t0 B1
    ST2(ga00, ga01, BUFE + la00, BUFE + la01); // t1 A0
    VMC(2); BAR;

    for (int i5 = 0; i5 < NTK / 2; ++i5) {
        bf16x8 af[8], ag[8], b0[4], b1[4];
        // ---- even tile (buf0); stages -> buf1 (dead) except gate
        // P1: rd A0-3(af) + B0-1; st B0(odd)->buf1
        RD_A(af, 0, 0); RD_B(b0, 0, 0);
        ST2(gb00, gb01, BUFE + lb00, BUFE + lb01);
        BAR; LGKM0;
        PRIO1; MF(0, 0, b0, af); PRIO0;
        // P2+P3 merged: rd B2-3 + A4-7(ag); st A1,B1(odd)->buf1
        RD_B(b1, 0, 2); RD_A(ag, 0, 4);
        ST2(ga10, ga11, BUFE + la10, BUFE + la11);
        ST2(gb10, gb11, BUFE + lb10, BUFE + lb11);
        BAR; LGKM0;
        PRIO1; MF(0, 2, b1, af); MF(4, 2, b1, ag); PRIO0;
        // P4 (gate): st A0(even+2)->buf0; counted gate for odd tile
        ST2(ga00, ga01, la00, la01);
        PRIO1; MF(4, 0, b0, ag); PRIO0;
        VMC(2); BAR;
        // ---- odd tile (buf1); stages -> buf0 (dead) except gate
        // P5
        RD_A(af, BUFE, 0); RD_B(b0, BUFE, 0);
        ST2(gb00, gb01, lb00, lb01);
        BAR; LGKM0;
        PRIO1; MF(0, 0, b0, af); PRIO0;
        // P6+P7 merged
        RD_B(b1, BUFE, 2); RD_A(ag, BUFE, 4);
        ST2(ga10, ga11, la10, la11);
        ST2(gb10, gb11, lb10, lb11);
        BAR; LGKM0;
        PRIO1; MF(0, 2, b1, af); MF(4, 2, b1, ag); PRIO0;
        // P8 (gate)
        ST2(ga00, ga01, BUFE + la00, BUFE + la01);
        PRIO1; MF(4, 0, b0, ag); PRIO0;
        VMC(2); BAR;
    }

    VMC(0);   // drain tail garbage loads before epilogue

#undef ST2
#undef RD_A
#undef RD_B
#undef MF
#undef BAR
#undef LGKM0
#undef VMC
#undef PRIO1
#undef PRIO0

    // epilogue (swapped D-layout): m = col (fr); n rows (fq*4+e) -> f32x4.
    // Nontemporal stores: output stream has zero reuse (clang ext-vector
    // type required by __builtin_nontemporal_store).
    f32x4  rqv4[4];
    int    nok[4];
    size_t ob[4];
    #pragma unroll
    for (int tn = 0; tn < 4; ++tn) {
        int n = n0 + wn0 + tn * 16 + fq * 4;
        nok[tn] = (n < NTOT);
        int nc = nok[tn] ? n : NTOT - 4;
        int q  = nc / IJ;
        int j  = nc - q * IJ;
        rqv4[tn] = *(const f32x4*)&qn[nc];
        ob[tn] = (size_t)q * OUTQ + j;
    }
    #pragma unroll
    for (int tm = 0; tm < 8; ++tm) {
        int m = m0 + wm0 + tm * 16 + fr;
        if (m < MROWS) {
            float rp = pn[m];
            #pragma unroll
            for (int tn = 0; tn < 4; ++tn) {
                if (nok[tn]) {
                    f32x4 a = acc[tm][tn];
                    f32x4 o;
                    o[0] = a[0] * __builtin_amdgcn_rcpf(fmaxf(rp * rqv4[tn][0], EPSV));
                    o[1] = a[1] * __builtin_amdgcn_rcpf(fmaxf(rp * rqv4[tn][1], EPSV));
                    o[2] = a[2] * __builtin_amdgcn_rcpf(fmaxf(rp * rqv4[tn][2], EPSV));
                    o[3] = a[3] * __builtin_amdgcn_rcpf(fmaxf(rp * rqv4[tn][3], EPSV));
                    __builtin_nontemporal_store(o,
                        (f32x4*)&out[ob[tn] + (size_t)m * IJ]);
                }
            }
        }
    }
}

// ---------------------------------------------------------------------------
// Fallback (round-1 kernel, known-passing) if ws_size is insufficient.
// ---------------------------------------------------------------------------
#define BMF 128
#define BNF 224
#define LPAD 40
__global__ __launch_bounds__(512, 4)
void sim_fallback(const float* __restrict__ proto,
                  const float* __restrict__ query,
                  float* __restrict__ out)
{
    __shared__ unsigned short As[BMF][LPAD];
    __shared__ unsigned short Bs[BNF][LPAD];
    __shared__ float redA[4][BMF];
    __shared__ float redB[2][BNF];
    __shared__ float rpS[BMF];
    __shared__ float rqS[BNF];

    const int tid = threadIdx.x;
    const int m0  = blockIdx.x * BMF;
    const int q   = blockIdx.y;

    const int mA  = tid & (BMF - 1);
    const int krA = tid >> 7;
    const int wiA = m0 + mA;
    const bool va = (wiA < MROWS);
    const int wA  = va ? (wiA / IJ) : 0;
    const int iA  = va ? (wiA - wA * IJ) : 0;
    const float* pA = proto + wA * (CD * IJ) + iA;

    const bool tb  = (tid < 448);
    const int jB   = tb ? (tid % BNF) : 0;
    const int krB  = tb ? (tid / BNF) : 0;
    const bool vb  = tb && (jB < IJ);
    const float* qB = query + q * (CD * IJ) + jB;

    float ssA = 0.f, ssB = 0.f;

    const int wv   = tid >> 6;
    const int lane = tid & 63;
    const int wm0  = (wv >> 1) * 32;
    const int wn0  = (wv & 1) * 112;
    const int fr   = lane & 15;
    const int fq   = lane >> 4;

    f32x4 acc[2][7];
    #pragma unroll
    for (int a = 0; a < 2; a++)
        #pragma unroll
        for (int b = 0; b < 7; b++)
            acc[a][b] = (f32x4){0.f, 0.f, 0.f, 0.f};

    for (int it = 0; it < CD / 32; ++it) {
        const int c0 = it * 32;
        {
            float v[8];
            #pragma unroll
            for (int e = 0; e < 8; e++) {
                int c = c0 + krA * 8 + e;
                v[e] = va ? pA[c * IJ] : 0.f;
            }
            #pragma unroll
            for (int e = 0; e < 8; e++) ssA += v[e] * v[e];
            union { unsigned short s[8]; uint4 u; } pk;
            #pragma unroll
            for (int e = 0; e < 8; e++) pk.s[e] = f2bf(v[e]);
            *(uint4*)&As[mA][krA * 8] = pk.u;
        }
        if (tb) {
            #pragma unroll
            for (int h = 0; h < 2; ++h) {
                float v[8];
                #pragma unroll
                for (int e = 0; e < 8; e++) {
                    int c = c0 + krB * 16 + h * 8 + e;
                    v[e] = vb ? qB[c * IJ] : 0.f;
                }
                #pragma unroll
                for (int e = 0; e < 8; e++) ssB += v[e] * v[e];
                union { unsigned short s[8]; uint4 u; } pk;
                #pragma unroll
                for (int e = 0; e < 8; e++) pk.s[e] = f2bf(v[e]);
                *(uint4*)&Bs[jB][krB * 16 + h * 8] = pk.u;
            }
        }
        __syncthreads();
        bf16x8 af[2], bfv[7];
        #pragma unroll
        for (int tm = 0; tm < 2; tm++)
            af[tm] = *(const bf16x8*)&As[wm0 + tm * 16 + fr][fq * 8];
        #pragma unroll
        for (int tn = 0; tn < 7; tn++)
            bfv[tn] = *(const bf16x8*)&Bs[wn0 + tn * 16 + fr][fq * 8];
        #pragma unroll
        for (int tm = 0; tm < 2; tm++)
            #pragma unroll
            for (int tn = 0; tn < 7; tn++)
                acc[tm][tn] = __builtin_amdgcn_mfma_f32_16x16x32_bf16(
                    af[tm], bfv[tn], acc[tm][tn], 0, 0, 0);
        __syncthreads();
    }

    redA[krA][mA] = ssA;
    if (tb) redB[krB][jB] = ssB;
    __syncthreads();
    if (tid < BMF) {
        rpS[tid] = sqrtf(redA[0][tid] + redA[1][tid] + redA[2][tid] + redA[3][tid]);
    } else if (tid >= 256 && tid < 256 + BNF) {
        int j = tid - 256;
        rqS[j] = sqrtf(redB[0][j] + redB[1][j]);
    }
    __syncthreads();

    #pragma unroll
    for (int tm = 0; tm < 2; tm++) {
        #pragma unroll
        for (int tn = 0; tn < 7; tn++) {
            #pragma unroll
            for (int r = 0; r < 4; r++) {
                int rl = wm0 + tm * 16 + fq * 4 + r;
                int cl = wn0 + tn * 16 + fr;
                int wi = m0 + rl;
                if (wi < MROWS && cl < IJ) {
                    float denom = fmaxf(rpS[rl] * rqS[cl], 1e-8f);
                    out[(size_t)(q * MROWS + wi) * IJ + cl] = acc[tm][tn][r] / denom;
                }
            }
        }
    }
}

// ---------------------------------------------------------------------------
extern "C" void kernel_launch(void* const* d_in, const int* in_sizes, int n_in,
                              void* d_out, int out_size, void* d_ws, size_t ws_size,
                              hipStream_t stream) {
    const float* proto = (const float*)d_in[0];
    const float* query = (const float*)d_in[1];
    float* out = (float*)d_out;

    // workspace layout
    const size_t off_pT = 0;                       // 1960*640*2 = 2,508,800
    const size_t off_qT = 2508800;                 // 58800*640*2 = 75,264,000
    const size_t off_pn = 77772800;                // 1960*4
    const size_t off_qn = 77780736;                // 58800*4
    const size_t need   = 78015936;

    if (ws_size < need) {
        dim3 grid((MROWS + BMF - 1) / BMF, QN);
        sim_fallback<<<grid, 512, 0, stream>>>(proto, query, out);
        return;
    }

    char* ws = (char*)d_ws;
    uint4* pT = (uint4*)(ws + off_pT);
    uint4* qT = (uint4*)(ws + off_qT);
    float* pn = (float*)(ws + off_pn);
    float* qn = (float*)(ws + off_qn);

    prep_all<<<dim3(4, QN + WN), 256, 0, stream>>>(proto, query, pT, qT, pn, qn);

    gemm_kernel<<<dim3(NWG), 512, 0, stream>>>(pT, qT, pn, qn, out);
}

// Round 14
// 547.788 us; speedup vs baseline: 1.0384x; 1.0384x over previous
//
#include <hip/hip_runtime.h>
#include <stdint.h>

#define QN    300
#define WN    10
#define CD    640
#define IJ    196
#define MROWS 1960              // WN*IJ
#define NTOT  58800             // QN*IJ
#define OUTQ  384160            // MROWS*IJ
#define EPSV  1e-8f

#define BM    256
#define BN    256
#define BK    64
#define BUFE  ((BM + BN) * BK)         // 32768 ushorts = 64 KB per buffer
#define NTK   (CD / BK)                // 10 K-tiles

#define MT_TILES 8                     // m tiles of 256 (pad 2048)
#define NT_TILES 230                   // n tiles of 256 (pad 58880)
#define NWG      (MT_TILES * NT_TILES) // 1840, divisible by 8
#define CPX      (NWG / 8)             // 230

typedef __attribute__((ext_vector_type(8))) short bf16x8;
typedef __attribute__((ext_vector_type(4))) float f32x4;

__device__ __forceinline__ unsigned short f2bf(float f) {
    uint32_t u = __float_as_uint(f);
    u += 0x7FFFu + ((u >> 16) & 1u);   // RNE
    return (unsigned short)(u >> 16);
}

__device__ __forceinline__ void gload16(const void* g, void* l) {
    __builtin_amdgcn_global_load_lds(
        (const __attribute__((address_space(1))) void*)g,
        (__attribute__((address_space(3))) void*)l,
        16, 0, 0);
}

// ---------------------------------------------------------------------------
// Combined pre-pass (ONE launch, round-10 verified): X[b][640][196] fp32 ->
// XT[row][640] bf16 (k contiguous) with the 3-bit swizzle baked per 16B unit
// within each 8-unit (64-elem) K-group: stored_unit = (u&8)|((u&7)^(row&7)),
// plus fp32 norms.  grid = (4, 310): y<300 -> query, else proto.
// ---------------------------------------------------------------------------
__global__ __launch_bounds__(256)
void prep_all(const float* __restrict__ proto, const float* __restrict__ query,
              uint4* __restrict__ pT, uint4* __restrict__ qT,
              float* __restrict__ pn, float* __restrict__ qn)
{
    __shared__ float T[128][65];
    __shared__ float ssL[64][17];

    const int bi = blockIdx.y;
    const bool isQ = (bi < QN);
    const int b  = isQ ? bi : bi - QN;
    const float* Xb = (isQ ? query : proto) + (size_t)b * (CD * IJ);
    uint4* XT   = isQ ? qT : pT;
    float* nrm  = isQ ? qn : pn;
    const int rowbase = b * IJ;

    const int i0 = blockIdx.x * 64;
    const int t  = threadIdx.x;

    const int cg = t >> 4;
    const int i4 = (t & 15) * 4;
    const int iv = i0 + i4;
    const bool liv = (iv <= IJ - 4);

    const int u   = t & 15;
    const int ilb = (t >> 4) * 4;

    float ss[4] = {0.f, 0.f, 0.f, 0.f};

    for (int cc = 0; cc < CD / 128; ++cc) {
        #pragma unroll
        for (int pass = 0; pass < 8; ++pass) {
            int cl = pass * 16 + cg;
            int c  = cc * 128 + cl;
            float4 v = make_float4(0.f, 0.f, 0.f, 0.f);
            if (liv) v = *(const float4*)&Xb[(size_t)c * IJ + iv];
            T[cl][i4 + 0] = v.x; T[cl][i4 + 1] = v.y;
            T[cl][i4 + 2] = v.z; T[cl][i4 + 3] = v.w;
        }
        __syncthreads();
        #pragma unroll
        for (int j = 0; j < 4; ++j) {
            int il = ilb + j;
            float v[8];
            #pragma unroll
            for (int r = 0; r < 8; ++r) { v[r] = T[u * 8 + r][il]; ss[j] += v[r] * v[r]; }
            int ig = i0 + il;
            if (ig < IJ) {
                union { unsigned short s[8]; uint4 q; } pk;
                #pragma unroll
                for (int r = 0; r < 8; ++r) pk.s[r] = f2bf(v[r]);
                int rowg = rowbase + ig;
                int us = (u & 8) | ((u & 7) ^ (rowg & 7));
                XT[(size_t)rowg * (CD / 8) + cc * 16 + us] = pk.q;
            }
        }
        __syncthreads();
    }

    #pragma unroll
    for (int j = 0; j < 4; ++j) ssL[ilb + j][u] = ss[j];
    __syncthreads();
    if (t < 64) {
        int ig = i0 + t;
        if (ig < IJ) {
            float s = 0.f;
            #pragma unroll
            for (int k = 0; k < 16; ++k) s += ssL[t][k];
            nrm[rowbase + ig] = sqrtf(s);
        }
    }
}

// ---------------------------------------------------------------------------
// GEMM.  C[m][n] = sum AT[m]*BT[n].  256x256 tile, BK=64, 8 waves (2M x 4N),
// per-wave 128x64 (acc[8][4]).  6 phases per 2 K-tiles (P2+P3 / P6+P7 merged
// via a second A reg-set ag[8]).  Counted vmcnt gates (VMC(2), never 0 in
// loop).  REGULAR float4 epilogue stores (round-13 lesson: nontemporal
// defeats L2 write-combining of the 16B/784B-stride store pattern -> 2x
// WRITE_SIZE; normal stores measured at ~ideal 485 MB).
// ---------------------------------------------------------------------------
__global__ __launch_bounds__(512, 2)
void gemm_kernel(const uint4* __restrict__ AT, const uint4* __restrict__ BT,
                 const float* __restrict__ pn, const float* __restrict__ qn,
                 float* __restrict__ out)
{
    __shared__ unsigned short lds[2 * BUFE];   // 128 KB

    const int bid = blockIdx.x;
    const int swz = (bid & 7) * CPX + (bid >> 3);   // bijective (1840%8==0)
    const int mt  = swz & (MT_TILES - 1);
    const int nt  = swz >> 3;
    const int m0  = mt * BM;
    const int n0  = nt * BN;

    const int t  = threadIdx.x;
    const int w  = t >> 6, l = t & 63;
    const int fr = l & 15, fq = l >> 4;
    const int wm0 = (w >> 2) * 128;   // 2 M-waves
    const int wn0 = (w & 3) * 64;     // 4 N-waves

    const int lr = l >> 3, lu = l & 7;
    int ra00 = m0 +   0 + w * 8 + lr; if (ra00 > MROWS - 1) ra00 = MROWS - 1;
    int ra01 = m0 +  64 + w * 8 + lr; if (ra01 > MROWS - 1) ra01 = MROWS - 1;
    int ra10 = m0 + 128 + w * 8 + lr; if (ra10 > MROWS - 1) ra10 = MROWS - 1;
    int ra11 = m0 + 192 + w * 8 + lr; if (ra11 > MROWS - 1) ra11 = MROWS - 1;
    int rb00 = n0 +   0 + w * 8 + lr; if (rb00 > NTOT - 1) rb00 = NTOT - 1;
    int rb01 = n0 +  64 + w * 8 + lr; if (rb01 > NTOT - 1) rb01 = NTOT - 1;
    int rb10 = n0 + 128 + w * 8 + lr; if (rb10 > NTOT - 1) rb10 = NTOT - 1;
    int rb11 = n0 + 192 + w * 8 + lr; if (rb11 > NTOT - 1) rb11 = NTOT - 1;
    const uint4* ga00 = AT + (size_t)ra00 * 80 + lu;
    const uint4* ga01 = AT + (size_t)ra01 * 80 + lu;
    const uint4* ga10 = AT + (size_t)ra10 * 80 + lu;
    const uint4* ga11 = AT + (size_t)ra11 * 80 + lu;
    const uint4* gb00 = BT + (size_t)rb00 * 80 + lu;
    const uint4* gb01 = BT + (size_t)rb01 * 80 + lu;
    const uint4* gb10 = BT + (size_t)rb10 * 80 + lu;
    const uint4* gb11 = BT + (size_t)rb11 * 80 + lu;
    const int la00 = (  0 + w * 8) * 64;
    const int la01 = ( 64 + w * 8) * 64;
    const int la10 = (128 + w * 8) * 64;
    const int la11 = (192 + w * 8) * 64;
    const int lb00 = BM * 64 + (  0 + w * 8) * 64;
    const int lb01 = BM * 64 + ( 64 + w * 8) * 64;
    const int lb10 = BM * 64 + (128 + w * 8) * 64;
    const int lb11 = BM * 64 + (192 + w * 8) * 64;

    const int fqS0 = fq << 3;
    const int fqS1 = (fq + 4) << 3;
    int baA[8], kyA[8], baB[4], kyB[4];
    #pragma unroll
    for (int i = 0; i < 8; ++i) {
        int rowa = wm0 + i * 16 + fr;
        baA[i] = rowa * 64;  kyA[i] = (rowa & 7) << 3;
    }
    #pragma unroll
    for (int i = 0; i < 4; ++i) {
        int rowb = wn0 + i * 16 + fr;
        baB[i] = BM * 64 + rowb * 64;  kyB[i] = (rowb & 7) << 3;
    }

    f32x4 acc[8][4];
    #pragma unroll
    for (int a = 0; a < 8; ++a)
        #pragma unroll
        for (int bb = 0; bb < 4; ++bb)
            acc[a][bb] = (f32x4){0.f, 0.f, 0.f, 0.f};

#define ST2(PA, PB, LA, LB)                                               \
    gload16(PA, (char*)&lds[(LA)]); PA += 8;                              \
    gload16(PB, (char*)&lds[(LB)]); PB += 8;

#define RD_A(AF, OC, G)                                                   \
    _Pragma("unroll")                                                     \
    for (int mm = 0; mm < 4; ++mm) {                                      \
        AF[mm]   = *(const bf16x8*)&lds[(OC) + baA[(G)+mm]                \
                                        + (fqS0 ^ kyA[(G)+mm])];          \
        AF[4+mm] = *(const bf16x8*)&lds[(OC) + baA[(G)+mm]                \
                                        + (fqS1 ^ kyA[(G)+mm])];          \
    }
#define RD_B(BV, OC, G)                                                   \
    _Pragma("unroll")                                                     \
    for (int nn = 0; nn < 2; ++nn) {                                      \
        BV[nn]   = *(const bf16x8*)&lds[(OC) + baB[(G)+nn]                \
                                        + (fqS0 ^ kyB[(G)+nn])];          \
        BV[2+nn] = *(const bf16x8*)&lds[(OC) + baB[(G)+nn]                \
                                        + (fqS1 ^ kyB[(G)+nn])];          \
    }
#define MF(MB, NB, BV, AF)                                                \
    _Pragma("unroll")                                                     \
    for (int ks = 0; ks < 2; ++ks)                                        \
        _Pragma("unroll")                                                 \
        for (int mm = 0; mm < 4; ++mm)                                    \
            _Pragma("unroll")                                             \
            for (int nn = 0; nn < 2; ++nn)                                \
                acc[(MB)+mm][(NB)+nn] =                                   \
                    __builtin_amdgcn_mfma_f32_16x16x32_bf16(              \
                        BV[ks*2+nn], AF[ks*4+mm],                         \
                        acc[(MB)+mm][(NB)+nn], 0, 0, 0);

#define BAR    __builtin_amdgcn_s_barrier()
#define LGKM0  do { asm volatile("s_waitcnt lgkmcnt(0)" ::: "memory");    \
                    __builtin_amdgcn_sched_barrier(0); } while (0)
#define VMC(N) asm volatile("s_waitcnt vmcnt(" #N ")" ::: "memory")
#define PRIO1  __builtin_amdgcn_s_setprio(1)
#define PRIO0  __builtin_amdgcn_s_setprio(0)

    // prologue: tile0 fully -> buf0; tile1's A0 -> buf1.  10 loads;
    // VMC(2): tile0's 8 landed, tile1-A0 pair in flight.
    ST2(ga00, ga01, la00, la01);               // t0 A0
    ST2(gb00, gb01, lb00, lb01);               // t0 B0
    ST2(ga10, ga11, la10, la11);               // t0 A1
    ST2(gb10, gb11, lb10, lb11);               // t0 B1
    ST2(ga00, ga01, BUFE + la00, BUFE + la01); // t1 A0
    VMC(2); BAR;

    for (int i5 = 0; i5 < NTK / 2; ++i5) {
        bf16x8 af[8], ag[8], b0[4], b1[4];
        // ---- even tile (buf0); stages -> buf1 (dead) except gate
        // P1: rd A0-3(af) + B0-1; st B0(odd)->buf1
        RD_A(af, 0, 0); RD_B(b0, 0, 0);
        ST2(gb00, gb01, BUFE + lb00, BUFE + lb01);
        BAR; LGKM0;
        PRIO1; MF(0, 0, b0, af); PRIO0;
        // P2+P3 merged: rd B2-3 + A4-7(ag); st A1,B1(odd)->buf1
        RD_B(b1, 0, 2); RD_A(ag, 0, 4);
        ST2(ga10, ga11, BUFE + la10, BUFE + la11);
        ST2(gb10, gb11, BUFE + lb10, BUFE + lb11);
        BAR; LGKM0;
        PRIO1; MF(0, 2, b1, af); MF(4, 2, b1, ag); PRIO0;
        // P4 (gate): st A0(even+2)->buf0; counted gate for odd tile
        ST2(ga00, ga01, la00, la01);
        PRIO1; MF(4, 0, b0, ag); PRIO0;
        VMC(2); BAR;
        // ---- odd tile (buf1); stages -> buf0 (dead) except gate
        // P5
        RD_A(af, BUFE, 0); RD_B(b0, BUFE, 0);
        ST2(gb00, gb01, lb00, lb01);
        BAR; LGKM0;
        PRIO1; MF(0, 0, b0, af); PRIO0;
        // P6+P7 merged
        RD_B(b1, BUFE, 2); RD_A(ag, BUFE, 4);
        ST2(ga10, ga11, la10, la11);
        ST2(gb10, gb11, lb10, lb11);
        BAR; LGKM0;
        PRIO1; MF(0, 2, b1, af); MF(4, 2, b1, ag); PRIO0;
        // P8 (gate)
        ST2(ga00, ga01, BUFE + la00, BUFE + la01);
        PRIO1; MF(4, 0, b0, ag); PRIO0;
        VMC(2); BAR;
    }

    VMC(0);   // drain tail garbage loads before epilogue

#undef ST2
#undef RD_A
#undef RD_B
#undef MF
#undef BAR
#undef LGKM0
#undef VMC
#undef PRIO1
#undef PRIO0

    // epilogue (swapped D-layout): m = col (fr); n rows (fq*4+e) -> float4.
    // Regular stores (L2 write-combining merges the 16B/784B-stride pattern).
    float4 rqv4[4];
    int    nok[4];
    size_t ob[4];
    #pragma unroll
    for (int tn = 0; tn < 4; ++tn) {
        int n = n0 + wn0 + tn * 16 + fq * 4;
        nok[tn] = (n < NTOT);
        int nc = nok[tn] ? n : NTOT - 4;
        int q  = nc / IJ;
        int j  = nc - q * IJ;
        rqv4[tn] = *(const float4*)&qn[nc];
        ob[tn] = (size_t)q * OUTQ + j;
    }
    #pragma unroll
    for (int tm = 0; tm < 8; ++tm) {
        int m = m0 + wm0 + tm * 16 + fr;
        if (m < MROWS) {
            float rp = pn[m];
            #pragma unroll
            for (int tn = 0; tn < 4; ++tn) {
                if (nok[tn]) {
                    f32x4 a = acc[tm][tn];
                    float4 o;
                    o.x = a[0] * __builtin_amdgcn_rcpf(fmaxf(rp * rqv4[tn].x, EPSV));
                    o.y = a[1] * __builtin_amdgcn_rcpf(fmaxf(rp * rqv4[tn].y, EPSV));
                    o.z = a[2] * __builtin_amdgcn_rcpf(fmaxf(rp * rqv4[tn].z, EPSV));
                    o.w = a[3] * __builtin_amdgcn_rcpf(fmaxf(rp * rqv4[tn].w, EPSV));
                    *(float4*)&out[ob[tn] + (size_t)m * IJ] = o;
                }
            }
        }
    }
}

// ---------------------------------------------------------------------------
// Fallback (round-1 kernel, known-passing) if ws_size is insufficient.
// ---------------------------------------------------------------------------
#define BMF 128
#define BNF 224
#define LPAD 40
__global__ __launch_bounds__(512, 4)
void sim_fallback(const float* __restrict__ proto,
                  const float* __restrict__ query,
                  float* __restrict__ out)
{
    __shared__ unsigned short As[BMF][LPAD];
    __shared__ unsigned short Bs[BNF][LPAD];
    __shared__ float redA[4][BMF];
    __shared__ float redB[2][BNF];
    __shared__ float rpS[BMF];
    __shared__ float rqS[BNF];

    const int tid = threadIdx.x;
    const int m0  = blockIdx.x * BMF;
    const int q   = blockIdx.y;

    const int mA  = tid & (BMF - 1);
    const int krA = tid >> 7;
    const int wiA = m0 + mA;
    const bool va = (wiA < MROWS);
    const int wA  = va ? (wiA / IJ) : 0;
    const int iA  = va ? (wiA - wA * IJ) : 0;
    const float* pA = proto + wA * (CD * IJ) + iA;

    const bool tb  = (tid < 448);
    const int jB   = tb ? (tid % BNF) : 0;
    const int krB  = tb ? (tid / BNF) : 0;
    const bool vb  = tb && (jB < IJ);
    const float* qB = query + q * (CD * IJ) + jB;

    float ssA = 0.f, ssB = 0.f;

    const int wv   = tid >> 6;
    const int lane = tid & 63;
    const int wm0  = (wv >> 1) * 32;
    const int wn0  = (wv & 1) * 112;
    const int fr   = lane & 15;
    const int fq   = lane >> 4;

    f32x4 acc[2][7];
    #pragma unroll
    for (int a = 0; a < 2; a++)
        #pragma unroll
        for (int b = 0; b < 7; b++)
            acc[a][b] = (f32x4){0.f, 0.f, 0.f, 0.f};

    for (int it = 0; it < CD / 32; ++it) {
        const int c0 = it * 32;
        {
            float v[8];
            #pragma unroll
            for (int e = 0; e < 8; e++) {
                int c = c0 + krA * 8 + e;
                v[e] = va ? pA[c * IJ] : 0.f;
            }
            #pragma unroll
            for (int e = 0; e < 8; e++) ssA += v[e] * v[e];
            union { unsigned short s[8]; uint4 u; } pk;
            #pragma unroll
            for (int e = 0; e < 8; e++) pk.s[e] = f2bf(v[e]);
            *(uint4*)&As[mA][krA * 8] = pk.u;
        }
        if (tb) {
            #pragma unroll
            for (int h = 0; h < 2; ++h) {
                float v[8];
                #pragma unroll
                for (int e = 0; e < 8; e++) {
                    int c = c0 + krB * 16 + h * 8 + e;
                    v[e] = vb ? qB[c * IJ] : 0.f;
                }
                #pragma unroll
                for (int e = 0; e < 8; e++) ssB += v[e] * v[e];
                union { unsigned short s[8]; uint4 u; } pk;
                #pragma unroll
                for (int e = 0; e < 8; e++) pk.s[e] = f2bf(v[e]);
                *(uint4*)&Bs[jB][krB * 16 + h * 8] = pk.u;
            }
        }
        __syncthreads();
        bf16x8 af[2], bfv[7];
        #pragma unroll
        for (int tm = 0; tm < 2; tm++)
            af[tm] = *(const bf16x8*)&As[wm0 + tm * 16 + fr][fq * 8];
        #pragma unroll
        for (int tn = 0; tn < 7; tn++)
            bfv[tn] = *(const bf16x8*)&Bs[wn0 + tn * 16 + fr][fq * 8];
        #pragma unroll
        for (int tm = 0; tm < 2; tm++)
            #pragma unroll
            for (int tn = 0; tn < 7; tn++)
                acc[tm][tn] = __builtin_amdgcn_mfma_f32_16x16x32_bf16(
                    af[tm], bfv[tn], acc[tm][tn], 0, 0, 0);
        __syncthreads();
    }

    redA[krA][mA] = ssA;
    if (tb) redB[krB][jB] = ssB;
    __syncthreads();
    if (tid < BMF) {
        rpS[tid] = sqrtf(redA[0][tid] + redA[1][tid] + redA[2][tid] + redA[3][tid]);
    } else if (tid >= 256 && tid < 256 + BNF) {
        int j = tid - 256;
        rqS[j] = sqrtf(redB[0][j] + redB[1][j]);
    }
    __syncthreads();

    #pragma unroll
    for (int tm = 0; tm < 2; tm++) {
        #pragma unroll
        for (int tn = 0; tn < 7; tn++) {
            #pragma unroll
            for (int r = 0; r < 4; r++) {
                int rl = wm0 + tm * 16 + fq * 4 + r;
                int cl = wn0 + tn * 16 + fr;
                int wi = m0 + rl;
                if (wi < MROWS && cl < IJ) {
                    float denom = fmaxf(rpS[rl] * rqS[cl], 1e-8f);
                    out[(size_t)(q * MROWS + wi) * IJ + cl] = acc[tm][tn][r] / denom;
                }
            }
        }
    }
}

// ---------------------------------------------------------------------------
extern "C" void kernel_launch(void* const* d_in, const int* in_sizes, int n_in,
                              void* d_out, int out_size, void* d_ws, size_t ws_size,
                              hipStream_t stream) {
    const float* proto = (const float*)d_in[0];
    const float* query = (const float*)d_in[1];
    float* out = (float*)d_out;

    // workspace layout
    const size_t off_pT = 0;                       // 1960*640*2 = 2,508,800
    const size_t off_qT = 2508800;                 // 58800*640*2 = 75,264,000
    const size_t off_pn = 77772800;                // 1960*4
    const size_t off_qn = 77780736;                // 58800*4
    const size_t need   = 78015936;

    if (ws_size < need) {
        dim3 grid((MROWS + BMF - 1) / BMF, QN);
        sim_fallback<<<grid, 512, 0, stream>>>(proto, query, out);
        return;
    }

    char* ws = (char*)d_ws;
    uint4* pT = (uint4*)(ws + off_pT);
    uint4* qT = (uint4*)(ws + off_qT);
    float* pn = (float*)(ws + off_pn);
    float* qn = (float*)(ws + off_qn);

    prep_all<<<dim3(4, QN + WN), 256, 0, stream>>>(proto, query, pT, qT, pn, qn);

    gemm_kernel<<<dim3(NWG), 512, 0, stream>>>(pT, qT, pn, qn, out);
}

// Round 15
// 352.642 us; speedup vs baseline: 1.6130x; 1.5534x over previous
//
#include <hip/hip_runtime.h>
#include <stdint.h>

#define QN    300
#define WN    10
#define CD    640
#define IJ    196
#define MROWS 1960              // WN*IJ
#define NTOT  58800             // QN*IJ
#define OUTQ  384160            // MROWS*IJ
#define EPSV  1e-8f

#define BM    256
#define BN    256
#define BK    64
#define BUFE  ((BM + BN) * BK)         // 32768 ushorts = 64 KB per buffer
#define NTK   (CD / BK)                // 10 K-tiles

#define MT_TILES 8                     // m tiles of 256 (pad 2048)
#define NT_TILES 230                   // n tiles of 256 (pad 58880)
#define NWG      (MT_TILES * NT_TILES) // 1840, divisible by 8
#define CPX      (NWG / 8)             // 230

typedef __attribute__((ext_vector_type(8))) short bf16x8;
typedef __attribute__((ext_vector_type(4))) float f32x4;

__device__ __forceinline__ unsigned short f2bf(float f) {
    uint32_t u = __float_as_uint(f);
    u += 0x7FFFu + ((u >> 16) & 1u);   // RNE
    return (unsigned short)(u >> 16);
}

__device__ __forceinline__ void gload16(const void* g, void* l) {
    __builtin_amdgcn_global_load_lds(
        (const __attribute__((address_space(1))) void*)g,
        (__attribute__((address_space(3))) void*)l,
        16, 0, 0);
}

// ---------------------------------------------------------------------------
// Combined pre-pass (ONE launch, round-10 verified): X[b][640][196] fp32 ->
// XT[row][640] bf16 (k contiguous) with the 3-bit swizzle baked per 16B unit
// within each 8-unit (64-elem) K-group: stored_unit = (u&8)|((u&7)^(row&7)),
// plus fp32 norms.  grid = (4, 310): y<300 -> query, else proto.
// ---------------------------------------------------------------------------
__global__ __launch_bounds__(256)
void prep_all(const float* __restrict__ proto, const float* __restrict__ query,
              uint4* __restrict__ pT, uint4* __restrict__ qT,
              float* __restrict__ pn, float* __restrict__ qn)
{
    __shared__ float T[128][65];
    __shared__ float ssL[64][17];

    const int bi = blockIdx.y;
    const bool isQ = (bi < QN);
    const int b  = isQ ? bi : bi - QN;
    const float* Xb = (isQ ? query : proto) + (size_t)b * (CD * IJ);
    uint4* XT   = isQ ? qT : pT;
    float* nrm  = isQ ? qn : pn;
    const int rowbase = b * IJ;

    const int i0 = blockIdx.x * 64;
    const int t  = threadIdx.x;

    const int cg = t >> 4;
    const int i4 = (t & 15) * 4;
    const int iv = i0 + i4;
    const bool liv = (iv <= IJ - 4);

    const int u   = t & 15;
    const int ilb = (t >> 4) * 4;

    float ss[4] = {0.f, 0.f, 0.f, 0.f};

    for (int cc = 0; cc < CD / 128; ++cc) {
        #pragma unroll
        for (int pass = 0; pass < 8; ++pass) {
            int cl = pass * 16 + cg;
            int c  = cc * 128 + cl;
            float4 v = make_float4(0.f, 0.f, 0.f, 0.f);
            if (liv) v = *(const float4*)&Xb[(size_t)c * IJ + iv];
            T[cl][i4 + 0] = v.x; T[cl][i4 + 1] = v.y;
            T[cl][i4 + 2] = v.z; T[cl][i4 + 3] = v.w;
        }
        __syncthreads();
        #pragma unroll
        for (int j = 0; j < 4; ++j) {
            int il = ilb + j;
            float v[8];
            #pragma unroll
            for (int r = 0; r < 8; ++r) { v[r] = T[u * 8 + r][il]; ss[j] += v[r] * v[r]; }
            int ig = i0 + il;
            if (ig < IJ) {
                union { unsigned short s[8]; uint4 q; } pk;
                #pragma unroll
                for (int r = 0; r < 8; ++r) pk.s[r] = f2bf(v[r]);
                int rowg = rowbase + ig;
                int us = (u & 8) | ((u & 7) ^ (rowg & 7));
                XT[(size_t)rowg * (CD / 8) + cc * 16 + us] = pk.q;
            }
        }
        __syncthreads();
    }

    #pragma unroll
    for (int j = 0; j < 4; ++j) ssL[ilb + j][u] = ss[j];
    __syncthreads();
    if (t < 64) {
        int ig = i0 + t;
        if (ig < IJ) {
            float s = 0.f;
            #pragma unroll
            for (int k = 0; k < 16; ++k) s += ssL[t][k];
            nrm[rowbase + ig] = sqrtf(s);
        }
    }
}

// ---------------------------------------------------------------------------
// GEMM (VERBATIM round-10 best: 275 us GEMM, MfmaUtil 23.6%, FETCH 137 MB,
// WRITE 485 MB, 0 bank conflicts).  C[m][n] = sum_c AT[m][c]*BT[n][c].
// 256x256 tile, BK=64, 8 waves (2M x 4N), per-wave 128x64 (acc[8][4] of
// 16x16x32).  8-phase / 2-K-tiles-per-iter, counted vmcnt (VMC(2) gates
// only, never 0 in loop), leading-only barriers on non-gate phases,
// swapped-operand MFMA -> float4 epilogue stores.
// Post-mortem notes kept from failed variants: A-direct-from-L2 (R11,
// -37%: per-lane 16B gathers at 160B stride expose L2 latency), nt stores
// (R13, 2x WRITE: defeats L2 write-combining), P2+P3 merge (R14, spills:
// af+ag+b0+b1 = 96 live frag VGPRs -> scratch traffic).
// ---------------------------------------------------------------------------
__global__ __launch_bounds__(512, 2)
void gemm_kernel(const uint4* __restrict__ AT, const uint4* __restrict__ BT,
                 const float* __restrict__ pn, const float* __restrict__ qn,
                 float* __restrict__ out)
{
    __shared__ unsigned short lds[2 * BUFE];   // 128 KB

    const int bid = blockIdx.x;
    const int swz = (bid & 7) * CPX + (bid >> 3);   // bijective (1840%8==0)
    const int mt  = swz & (MT_TILES - 1);
    const int nt  = swz >> 3;
    const int m0  = mt * BM;
    const int n0  = nt * BN;

    const int t  = threadIdx.x;
    const int w  = t >> 6, l = t & 63;
    const int fr = l & 15, fq = l >> 4;
    const int wm0 = (w >> 2) * 128;   // 2 M-waves
    const int wn0 = (w & 3) * 64;     // 4 N-waves

    const int lr = l >> 3, lu = l & 7;
    int ra00 = m0 +   0 + w * 8 + lr; if (ra00 > MROWS - 1) ra00 = MROWS - 1;
    int ra01 = m0 +  64 + w * 8 + lr; if (ra01 > MROWS - 1) ra01 = MROWS - 1;
    int ra10 = m0 + 128 + w * 8 + lr; if (ra10 > MROWS - 1) ra10 = MROWS - 1;
    int ra11 = m0 + 192 + w * 8 + lr; if (ra11 > MROWS - 1) ra11 = MROWS - 1;
    int rb00 = n0 +   0 + w * 8 + lr; if (rb00 > NTOT - 1) rb00 = NTOT - 1;
    int rb01 = n0 +  64 + w * 8 + lr; if (rb01 > NTOT - 1) rb01 = NTOT - 1;
    int rb10 = n0 + 128 + w * 8 + lr; if (rb10 > NTOT - 1) rb10 = NTOT - 1;
    int rb11 = n0 + 192 + w * 8 + lr; if (rb11 > NTOT - 1) rb11 = NTOT - 1;
    const uint4* ga00 = AT + (size_t)ra00 * 80 + lu;
    const uint4* ga01 = AT + (size_t)ra01 * 80 + lu;
    const uint4* ga10 = AT + (size_t)ra10 * 80 + lu;
    const uint4* ga11 = AT + (size_t)ra11 * 80 + lu;
    const uint4* gb00 = BT + (size_t)rb00 * 80 + lu;
    const uint4* gb01 = BT + (size_t)rb01 * 80 + lu;
    const uint4* gb10 = BT + (size_t)rb10 * 80 + lu;
    const uint4* gb11 = BT + (size_t)rb11 * 80 + lu;
    const int la00 = (  0 + w * 8) * 64;
    const int la01 = ( 64 + w * 8) * 64;
    const int la10 = (128 + w * 8) * 64;
    const int la11 = (192 + w * 8) * 64;
    const int lb00 = BM * 64 + (  0 + w * 8) * 64;
    const int lb01 = BM * 64 + ( 64 + w * 8) * 64;
    const int lb10 = BM * 64 + (128 + w * 8) * 64;
    const int lb11 = BM * 64 + (192 + w * 8) * 64;

    const int fqS0 = fq << 3;
    const int fqS1 = (fq + 4) << 3;
    int baA[8], kyA[8], baB[4], kyB[4];
    #pragma unroll
    for (int i = 0; i < 8; ++i) {
        int rowa = wm0 + i * 16 + fr;
        baA[i] = rowa * 64;  kyA[i] = (rowa & 7) << 3;
    }
    #pragma unroll
    for (int i = 0; i < 4; ++i) {
        int rowb = wn0 + i * 16 + fr;
        baB[i] = BM * 64 + rowb * 64;  kyB[i] = (rowb & 7) << 3;
    }

    f32x4 acc[8][4];
    #pragma unroll
    for (int a = 0; a < 8; ++a)
        #pragma unroll
        for (int bb = 0; bb < 4; ++bb)
            acc[a][bb] = (f32x4){0.f, 0.f, 0.f, 0.f};

#define ST2(PA, PB, LA, LB)                                               \
    gload16(PA, (char*)&lds[(LA)]); PA += 8;                              \
    gload16(PB, (char*)&lds[(LB)]); PB += 8;

#define RD_A(OC, G)                                                       \
    _Pragma("unroll")                                                     \
    for (int mm = 0; mm < 4; ++mm) {                                      \
        af[mm]   = *(const bf16x8*)&lds[(OC) + baA[(G)+mm]                \
                                        + (fqS0 ^ kyA[(G)+mm])];          \
        af[4+mm] = *(const bf16x8*)&lds[(OC) + baA[(G)+mm]                \
                                        + (fqS1 ^ kyA[(G)+mm])];          \
    }
#define RD_B(BV, OC, G)                                                   \
    _Pragma("unroll")                                                     \
    for (int nn = 0; nn < 2; ++nn) {                                      \
        BV[nn]   = *(const bf16x8*)&lds[(OC) + baB[(G)+nn]                \
                                        + (fqS0 ^ kyB[(G)+nn])];          \
        BV[2+nn] = *(const bf16x8*)&lds[(OC) + baB[(G)+nn]                \
                                        + (fqS1 ^ kyB[(G)+nn])];          \
    }
#define MF(MB, NB, BV)                                                    \
    _Pragma("unroll")                                                     \
    for (int ks = 0; ks < 2; ++ks)                                        \
        _Pragma("unroll")                                                 \
        for (int mm = 0; mm < 4; ++mm)                                    \
            _Pragma("unroll")                                             \
            for (int nn = 0; nn < 2; ++nn)                                \
                acc[(MB)+mm][(NB)+nn] =                                   \
                    __builtin_amdgcn_mfma_f32_16x16x32_bf16(              \
                        BV[ks*2+nn], af[ks*4+mm],                         \
                        acc[(MB)+mm][(NB)+nn], 0, 0, 0);

#define BAR    __builtin_amdgcn_s_barrier()
#define LGKM0  do { asm volatile("s_waitcnt lgkmcnt(0)" ::: "memory");    \
                    __builtin_amdgcn_sched_barrier(0); } while (0)
#define VMC(N) asm volatile("s_waitcnt vmcnt(" #N ")" ::: "memory")
#define PRIO1  __builtin_amdgcn_s_setprio(1)
#define PRIO0  __builtin_amdgcn_s_setprio(0)

    ST2(ga00, ga01, la00, la01);               // t0 A0
    ST2(gb00, gb01, lb00, lb01);               // t0 B0
    ST2(ga10, ga11, la10, la11);               // t0 A1
    ST2(gb10, gb11, lb10, lb11);               // t0 B1
    ST2(ga00, ga01, BUFE + la00, BUFE + la01); // t1 A0
    VMC(2); BAR;

    for (int i5 = 0; i5 < NTK / 2; ++i5) {
        bf16x8 af[8], b0[4], b1[4];
        // P1
        RD_A(0, 0); RD_B(b0, 0, 0);
        ST2(gb00, gb01, BUFE + lb00, BUFE + lb01);
        BAR; LGKM0;
        PRIO1; MF(0, 0, b0); PRIO0;
        // P2
        RD_B(b1, 0, 2);
        ST2(ga10, ga11, BUFE + la10, BUFE + la11);
        BAR; LGKM0;
        PRIO1; MF(0, 2, b1); PRIO0;
        // P3
        RD_A(0, 4);
        ST2(gb10, gb11, BUFE + lb10, BUFE + lb11);
        BAR; LGKM0;
        PRIO1; MF(4, 2, b1); PRIO0;
        // P4 (gate)
        ST2(ga00, ga01, la00, la01);
        PRIO1; MF(4, 0, b0); PRIO0;
        VMC(2); BAR;
        // P5
        RD_A(BUFE, 0); RD_B(b0, BUFE, 0);
        ST2(gb00, gb01, lb00, lb01);
        BAR; LGKM0;
        PRIO1; MF(0, 0, b0); PRIO0;
        // P6
        RD_B(b1, BUFE, 2);
        ST2(ga10, ga11, la10, la11);
        BAR; LGKM0;
        PRIO1; MF(0, 2, b1); PRIO0;
        // P7
        RD_A(BUFE, 4);
        ST2(gb10, gb11, lb10, lb11);
        BAR; LGKM0;
        PRIO1; MF(4, 2, b1); PRIO0;
        // P8 (gate)
        ST2(ga00, ga01, BUFE + la00, BUFE + la01);
        PRIO1; MF(4, 0, b0); PRIO0;
        VMC(2); BAR;
    }

    VMC(0);   // drain tail garbage loads before epilogue

#undef ST2
#undef RD_A
#undef RD_B
#undef MF
#undef BAR
#undef LGKM0
#undef VMC
#undef PRIO1
#undef PRIO0

    float4 rqv4[4];
    int    nok[4];
    size_t ob[4];
    #pragma unroll
    for (int tn = 0; tn < 4; ++tn) {
        int n = n0 + wn0 + tn * 16 + fq * 4;
        nok[tn] = (n < NTOT);
        int nc = nok[tn] ? n : NTOT - 4;
        int q  = nc / IJ;
        int j  = nc - q * IJ;
        rqv4[tn] = *(const float4*)&qn[nc];
        ob[tn] = (size_t)q * OUTQ + j;
    }
    #pragma unroll
    for (int tm = 0; tm < 8; ++tm) {
        int m = m0 + wm0 + tm * 16 + fr;
        if (m < MROWS) {
            float rp = pn[m];
            #pragma unroll
            for (int tn = 0; tn < 4; ++tn) {
                if (nok[tn]) {
                    f32x4 a = acc[tm][tn];
                    float4 o;
                    o.x = a[0] * __builtin_amdgcn_rcpf(fmaxf(rp * rqv4[tn].x, EPSV));
                    o.y = a[1] * __builtin_amdgcn_rcpf(fmaxf(rp * rqv4[tn].y, EPSV));
                    o.z = a[2] * __builtin_amdgcn_rcpf(fmaxf(rp * rqv4[tn].z, EPSV));
                    o.w = a[3] * __builtin_amdgcn_rcpf(fmaxf(rp * rqv4[tn].w, EPSV));
                    *(float4*)&out[ob[tn] + (size_t)m * IJ] = o;
                }
            }
        }
    }
}

// ---------------------------------------------------------------------------
// Fallback (round-1 kernel, known-passing) if ws_size is insufficient.
// ---------------------------------------------------------------------------
#define BMF 128
#define BNF 224
#define LPAD 40
__global__ __launch_bounds__(512, 4)
void sim_fallback(const float* __restrict__ proto,
                  const float* __restrict__ query,
                  float* __restrict__ out)
{
    __shared__ unsigned short As[BMF][LPAD];
    __shared__ unsigned short Bs[BNF][LPAD];
    __shared__ float redA[4][BMF];
    __shared__ float redB[2][BNF];
    __shared__ float rpS[BMF];
    __shared__ float rqS[BNF];

    const int tid = threadIdx.x;
    const int m0  = blockIdx.x * BMF;
    const int q   = blockIdx.y;

    const int mA  = tid & (BMF - 1);
    const int krA = tid >> 7;
    const int wiA = m0 + mA;
    const bool va = (wiA < MROWS);
    const int wA  = va ? (wiA / IJ) : 0;
    const int iA  = va ? (wiA - wA * IJ) : 0;
    const float* pA = proto + wA * (CD * IJ) + iA;

    const bool tb  = (tid < 448);
    const int jB   = tb ? (tid % BNF) : 0;
    const int krB  = tb ? (tid / BNF) : 0;
    const bool vb  = tb && (jB < IJ);
    const float* qB = query + q * (CD * IJ) + jB;

    float ssA = 0.f, ssB = 0.f;

    const int wv   = tid >> 6;
    const int lane = tid & 63;
    const int wm0  = (wv >> 1) * 32;
    const int wn0  = (wv & 1) * 112;
    const int fr   = lane & 15;
    const int fq   = lane >> 4;

    f32x4 acc[2][7];
    #pragma unroll
    for (int a = 0; a < 2; a++)
        #pragma unroll
        for (int b = 0; b < 7; b++)
            acc[a][b] = (f32x4){0.f, 0.f, 0.f, 0.f};

    for (int it = 0; it < CD / 32; ++it) {
        const int c0 = it * 32;
        {
            float v[8];
            #pragma unroll
            for (int e = 0; e < 8; e++) {
                int c = c0 + krA * 8 + e;
                v[e] = va ? pA[c * IJ] : 0.f;
            }
            #pragma unroll
            for (int e = 0; e < 8; e++) ssA += v[e] * v[e];
            union { unsigned short s[8]; uint4 u; } pk;
            #pragma unroll
            for (int e = 0; e < 8; e++) pk.s[e] = f2bf(v[e]);
            *(uint4*)&As[mA][krA * 8] = pk.u;
        }
        if (tb) {
            #pragma unroll
            for (int h = 0; h < 2; ++h) {
                float v[8];
                #pragma unroll
                for (int e = 0; e < 8; e++) {
                    int c = c0 + krB * 16 + h * 8 + e;
                    v[e] = vb ? qB[c * IJ] : 0.f;
                }
                #pragma unroll
                for (int e = 0; e < 8; e++) ssB += v[e] * v[e];
                union { unsigned short s[8]; uint4 u; } pk;
                #pragma unroll
                for (int e = 0; e < 8; e++) pk.s[e] = f2bf(v[e]);
                *(uint4*)&Bs[jB][krB * 16 + h * 8] = pk.u;
            }
        }
        __syncthreads();
        bf16x8 af[2], bfv[7];
        #pragma unroll
        for (int tm = 0; tm < 2; tm++)
            af[tm] = *(const bf16x8*)&As[wm0 + tm * 16 + fr][fq * 8];
        #pragma unroll
        for (int tn = 0; tn < 7; tn++)
            bfv[tn] = *(const bf16x8*)&Bs[wn0 + tn * 16 + fr][fq * 8];
        #pragma unroll
        for (int tm = 0; tm < 2; tm++)
            #pragma unroll
            for (int tn = 0; tn < 7; tn++)
                acc[tm][tn] = __builtin_amdgcn_mfma_f32_16x16x32_bf16(
                    af[tm], bfv[tn], acc[tm][tn], 0, 0, 0);
        __syncthreads();
    }

    redA[krA][mA] = ssA;
    if (tb) redB[krB][jB] = ssB;
    __syncthreads();
    if (tid < BMF) {
        rpS[tid] = sqrtf(redA[0][tid] + redA[1][tid] + redA[2][tid] + redA[3][tid]);
    } else if (tid >= 256 && tid < 256 + BNF) {
        int j = tid - 256;
        rqS[j] = sqrtf(redB[0][j] + redB[1][j]);
    }
    __syncthreads();

    #pragma unroll
    for (int tm = 0; tm < 2; tm++) {
        #pragma unroll
        for (int tn = 0; tn < 7; tn++) {
            #pragma unroll
            for (int r = 0; r < 4; r++) {
                int rl = wm0 + tm * 16 + fq * 4 + r;
                int cl = wn0 + tn * 16 + fr;
                int wi = m0 + rl;
                if (wi < MROWS && cl < IJ) {
                    float denom = fmaxf(rpS[rl] * rqS[cl], 1e-8f);
                    out[(size_t)(q * MROWS + wi) * IJ + cl] = acc[tm][tn][r] / denom;
                }
            }
        }
    }
}

// ---------------------------------------------------------------------------
extern "C" void kernel_launch(void* const* d_in, const int* in_sizes, int n_in,
                              void* d_out, int out_size, void* d_ws, size_t ws_size,
                              hipStream_t stream) {
    const float* proto = (const float*)d_in[0];
    const float* query = (const float*)d_in[1];
    float* out = (float*)d_out;

    // workspace layout
    const size_t off_pT = 0;                       // 1960*640*2 = 2,508,800
    const size_t off_qT = 2508800;                 // 58800*640*2 = 75,264,000
    const size_t off_pn = 77772800;                // 1960*4
    const size_t off_qn = 77780736;                // 58800*4
    const size_t need   = 78015936;

    if (ws_size < need) {
        dim3 grid((MROWS + BMF - 1) / BMF, QN);
        sim_fallback<<<grid, 512, 0, stream>>>(proto, query, out);
        return;
    }

    char* ws = (char*)d_ws;
    uint4* pT = (uint4*)(ws + off_pT);
    uint4* qT = (uint4*)(ws + off_qT);
    float* pn = (float*)(ws + off_pn);
    float* qn = (float*)(ws + off_qn);

    prep_all<<<dim3(4, QN + WN), 256, 0, stream>>>(proto, query, pT, qT, pn, qn);

    gemm_kernel<<<dim3(NWG), 512, 0, stream>>>(pT, qT, pn, qn, out);
}